// Round 7
// baseline (108.928 us; speedup 1.0000x reference)
//
#include <hip/hip_runtime.h>
#include <stdint.h>

#define BS 256
#define CPB 4          // chunks (of BS rows) per block in count/copy

typedef unsigned long long u64;
typedef float f32x4 __attribute__((ext_vector_type(4)));

__device__ __forceinline__ void nt_store4(f32x4* p, f32x4 v) { __builtin_nontemporal_store(v, p); }
__device__ __forceinline__ f32x4 nt_load4(const f32x4* p) { return __builtin_nontemporal_load(p); }
__device__ __forceinline__ void nt_storef(float* p, float v) { __builtin_nontemporal_store(v, p); }
__device__ __forceinline__ float nt_loadf(const float* p) { return __builtin_nontemporal_load(p); }
__device__ __forceinline__ int nt_loadi(const int* p) { return __builtin_nontemporal_load(p); }

// ---------------- Node 1: per-(segment,slot) partial min + zero ws_total ----
__global__ __launch_bounds__(BS)
void k_segmin(const float* __restrict__ score, const int* __restrict__ track,
              const int* __restrict__ rs, int B, int SPS,
              float* __restrict__ part_min, int* __restrict__ ws_total) {
    int b = blockIdx.x;
    if (b == 0 && threadIdx.x == 0) *ws_total = 0;
    int s = b / SPS, j = b - s * SPS;
    int r0 = rs[s], r1 = rs[s + 1];
    int len = r1 - r0;
    int per = (len + SPS - 1) / SPS;
    int a = r0 + j * per;
    int e = min(r1, a + per);
    float m = INFINITY;
    for (int i = a + (int)threadIdx.x; i < e; i += BS)
        m = fminf(m, track[i] ? 0.0f : score[i]);
    for (int d = 32; d > 0; d >>= 1) m = fminf(m, __shfl_down(m, d));
    __shared__ float wmin[BS / 64];
    if ((threadIdx.x & 63) == 0) wmin[threadIdx.x >> 6] = m;
    __syncthreads();
    if (threadIdx.x == 0) {
        float mm = wmin[0];
        for (int k = 1; k < BS / 64; ++k) mm = fminf(mm, wmin[k]);
        part_min[b] = mm;
    }
}

// ---------------- Node 2: threshold + ballots -> masks + counts + total -----
__global__ __launch_bounds__(BS)
void k_count(const float* __restrict__ score, const int* __restrict__ track,
             const float* __restrict__ part_min, int N, int B, int SPS,
             u64* __restrict__ gmask, int* __restrict__ cnts,
             int* __restrict__ ws_total) {
    const int b = blockIdx.x, tid = threadIdx.x;
    const int w = tid >> 6, lane = tid & 63;
    __shared__ float shT;
    __shared__ u64 smask[CPB * 4];

    if (tid < 64) {
        float m = -INFINITY;
        for (int s = tid; s < B; s += 64) {
            float mn = INFINITY;
            for (int j = 0; j < SPS; ++j) mn = fminf(mn, part_min[s * SPS + j]);
            m = fmaxf(m, mn);
        }
        for (int d = 32; d > 0; d >>= 1) m = fmaxf(m, __shfl_xor(m, d));
        if (tid == 0) shT = (m < 0.1f) ? 0.1f : (m + 1e-7f);
    }
    __syncthreads();
    const float T = shT;

    const long Rb = (long)b * CPB * BS;
    for (int c = 0; c < CPB; ++c) {
        long i = Rb + (long)c * BS + tid;
        bool pred = (i < N) && ((nt_loadi(&track[i]) ? 0.0f : nt_loadf(&score[i])) <= T);
        u64 bal = __ballot(pred);
        if (lane == 0) smask[c * 4 + w] = bal;
    }
    __syncthreads();
    if (tid < CPB * 4) gmask[(long)b * CPB * 4 + tid] = smask[tid];
    if (tid == 0) {
        int c = 0;
        for (int k = 0; k < CPB * 4; ++k) c += __popcll(smask[k]);
        cnts[b] = c;
        atomicAdd(ws_total, c);
    }
}

// ---------------- Node 3: prefix + compacted copy + new_rs ------------------
__global__ __launch_bounds__(BS)
void k_copy(const float* __restrict__ x, const int* __restrict__ rsp,
            const u64* __restrict__ gmask, const int* __restrict__ cnts,
            int N, int B, int F, int G2,
            float* __restrict__ out_x, float* __restrict__ out_rs,
            float* __restrict__ out_old, float* __restrict__ out_idx,
            float* __restrict__ out_nsel) {
    const int b = blockIdx.x, tid = threadIdx.x;
    const int w = tid >> 6, lane = tid & 63;
    const int RPB = CPB * BS;
    const int Rb = b * RPB;
    const int Lact = min(RPB, N - Rb);

    __shared__ u64 smask[CPB * 4];
    __shared__ int chunkcnt[CPB];
    __shared__ int rows[CPB * BS];
    __shared__ int shBase, shTot;

    if (tid < CPB * 4) smask[tid] = gmask[(long)b * CPB * 4 + tid];

    // exclusive prefix of cnts up to b + grand total (redundant, L2-hot)
    if (tid < 64) {
        int pre = 0, tot = 0;
        for (int k = tid; k < G2; k += 64) {
            int c = cnts[k];
            tot += c;
            pre += (k < b) ? c : 0;
        }
        for (int d = 32; d > 0; d >>= 1) {
            pre += __shfl_down(pre, d);
            tot += __shfl_down(tot, d);
        }
        if (tid == 0) { shBase = pre; shTot = tot; }
    }
    __syncthreads();
    if (tid < CPB) {
        const u64* mw = &smask[tid * 4];
        chunkcnt[tid] = __popcll(mw[0]) + __popcll(mw[1]) + __popcll(mw[2]) + __popcll(mw[3]);
    }
    __syncthreads();
    const int myBase = shBase, total = shTot;

    if (b == 0 && tid == 0) { out_nsel[0] = (float)total; out_old[0] = (float)N; }

    // build compacted row list in LDS + write indices output
    int bcnt = 0;
    {
        int basec = 0;
        for (int c = 0; c < CPB; ++c) {
            u64 mybal = smask[c * 4 + w];
            int wb = 0;
            for (int k = 0; k < w; ++k) wb += __popcll(smask[c * 4 + k]);
            if ((mybal >> (unsigned)lane) & 1ULL) {
                int rank = basec + wb + __popcll(mybal & ((1ULL << (unsigned)lane) - 1ULL));
                int row = Rb + c * BS + tid;
                rows[rank] = row;
                nt_storef(&out_idx[(long)myBase + rank], (float)row);
            }
            basec += chunkcnt[c];
        }
        bcnt = basec;
    }
    __syncthreads();

    const int Fv = F >> 2;
    const bool vec = ((F & 3) == 0) && (Fv > 0) && (BS % Fv == 0);
    const f32x4* x4 = (const f32x4*)x;
    f32x4* out4 = (f32x4*)out_x;

    // flat barrier-free gather/copy of selected rows (NT both ways)
    if (vec) {
        int r0 = tid / Fv, cc = tid - r0 * Fv, rstep = BS / Fv;
        for (int r = r0; r < bcnt; r += rstep) {
            f32x4 v = nt_load4(&x4[(long)rows[r] * Fv + cc]);
            nt_store4(&out4[((long)myBase + r) * Fv + cc], v);
        }
    } else {
        for (int e = tid; e < bcnt * F; e += BS) {
            int r = e / F, cc = e - r * F;
            nt_storef(&out_x[((long)myBase + r) * F + cc],
                      nt_loadf(&x[(long)rows[r] * F + cc]));
        }
    }

    // new_rs boundaries owned by this block (pos>=N -> last block)
    for (int s = tid; s <= B; s += BS) {
        int pos = rsp[s];
        if (pos >= Rb && pos < Rb + Lact) {
            int rel = pos - Rb;
            int nw = rel >> 6, rem = rel & 63;
            int cnt = 0;
            for (int k = 0; k < nw; ++k) cnt += __popcll(smask[k]);
            if (rem) cnt += __popcll(smask[nw] & ((1ULL << (unsigned)rem) - 1ULL));
            out_rs[s] = (float)(myBase + cnt);
        } else if (b == G2 - 1 && pos >= N) {
            out_rs[s] = (float)total;
        }
    }
}

// ---------------- Node 4: streaming tails (zeros + -1) ----------------------
__global__ __launch_bounds__(BS)
void k_zero(const int* __restrict__ ws_total, int N, int F,
            float* __restrict__ out_x, float* __restrict__ out_idx) {
    const int total = *ws_total;
    const long stride = (long)gridDim.x * BS;
    const long off = (long)blockIdx.x * BS + threadIdx.x;
    if ((F & 3) == 0) {
        const int Fv = F >> 2;
        f32x4* out4 = (f32x4*)out_x;
        f32x4 z = (f32x4)(0.0f);
        long e0 = (long)total * Fv, e1 = (long)N * Fv;
        for (long e = e0 + off; e < e1; e += stride) nt_store4(&out4[e], z);
    } else {
        long e0 = (long)total * F, e1 = (long)N * F;
        for (long e = e0 + off; e < e1; e += stride) nt_storef(&out_x[e], 0.0f);
    }
    for (long t = total + off; t < N; t += stride) nt_storef(&out_idx[t], -1.0f);
}

extern "C" void kernel_launch(void* const* d_in, const int* in_sizes, int n_in,
                              void* d_out, int out_size, void* d_ws, size_t ws_size,
                              hipStream_t stream) {
    const float* x     = (const float*)d_in[0];
    const float* score = (const float*)d_in[1];
    const int*   track = (const int*)d_in[2];
    const int*   rs    = (const int*)d_in[3];

    int N = in_sizes[1];            // rows
    int F = in_sizes[0] / N;        // 32
    int B = in_sizes[3] - 1;        // 64

    int nchunks = (N + BS - 1) / BS;
    int G2 = (nchunks + CPB - 1) / CPB;

    int SPS = B > 0 ? (1024 / B) : 1;
    if (SPS < 1) SPS = 1;
    if (SPS > 64) SPS = 64;
    int G1 = B * SPS;

    // workspace layout
    float* part_min = (float*)d_ws;                 // G1 floats
    int*   ws_total = (int*)(part_min + G1);        // 1 int
    int*   cnts     = ws_total + 1;                 // G2 ints
    u64*   gmask    = (u64*)(((uintptr_t)(cnts + G2) + 15) & ~(uintptr_t)15); // G2*CPB*4

    // output layout (all float32 values)
    float* out      = (float*)d_out;
    long off_rs   = (long)N * F;
    long off_old  = off_rs + (B + 1);
    long off_idx  = off_old + 1;
    long off_nsel = off_idx + N;

    float* out_x    = out;
    float* out_rs   = out + off_rs;
    float* out_old  = out + off_old;
    float* out_idx  = out + off_idx;
    float* out_nsel = out + off_nsel;

    k_segmin<<<G1, BS, 0, stream>>>(score, track, rs, B, SPS, part_min, ws_total);
    k_count<<<G2, BS, 0, stream>>>(score, track, part_min, N, B, SPS, gmask, cnts, ws_total);
    k_copy<<<G2, BS, 0, stream>>>(x, rs, gmask, cnts, N, B, F, G2,
                                  out_x, out_rs, out_old, out_idx, out_nsel);
    k_zero<<<2048, BS, 0, stream>>>(ws_total, N, F, out_x, out_idx);
}

// Round 8
// 95.535 us; speedup vs baseline: 1.1402x; 1.1402x over previous
//
#include <hip/hip_runtime.h>
#include <stdint.h>

#define BS 256
#define CPB 4
#define RPB (CPB * BS)     // 1024 rows per count-block == dst rows per write-block
#define WPC (RPB / 64)     // 16 mask words per count-block

typedef unsigned long long u64;
typedef float f32x4 __attribute__((ext_vector_type(4)));

// ---------------- Node 1: per-(segment,slot) partial min --------------------
__global__ __launch_bounds__(BS)
void k_segmin(const float* __restrict__ score, const int* __restrict__ track,
              const int* __restrict__ rs, int B, int SPS,
              float* __restrict__ part_min) {
    int b = blockIdx.x;
    int s = b / SPS, j = b - s * SPS;
    int r0 = rs[s], r1 = rs[s + 1];
    int len = r1 - r0;
    int per = (len + SPS - 1) / SPS;
    int a = r0 + j * per;
    int e = min(r1, a + per);
    float m = INFINITY;
    for (int i = a + (int)threadIdx.x; i < e; i += BS)
        m = fminf(m, track[i] ? 0.0f : score[i]);
    for (int d = 32; d > 0; d >>= 1) m = fminf(m, __shfl_down(m, d));
    __shared__ float wmin[BS / 64];
    if ((threadIdx.x & 63) == 0) wmin[threadIdx.x >> 6] = m;
    __syncthreads();
    if (threadIdx.x == 0) {
        float mm = wmin[0];
        for (int k = 1; k < BS / 64; ++k) mm = fminf(mm, wmin[k]);
        part_min[b] = mm;
    }
}

// ---------------- Node 2: threshold + ballots -> linear masks + counts ------
__global__ __launch_bounds__(BS)
void k_count(const float* __restrict__ score, const int* __restrict__ track,
             const float* __restrict__ part_min, int N, int B, int SPS,
             u64* __restrict__ gmask, int* __restrict__ cnts) {
    const int b = blockIdx.x, tid = threadIdx.x;
    const int w = tid >> 6, lane = tid & 63;
    __shared__ float shT;
    __shared__ u64 smask[WPC];

    if (tid < 64) {
        float m = -INFINITY;
        for (int s = tid; s < B; s += 64) {
            float mn = INFINITY;
            for (int j = 0; j < SPS; ++j) mn = fminf(mn, part_min[s * SPS + j]);
            m = fmaxf(m, mn);
        }
        for (int d = 32; d > 0; d >>= 1) m = fmaxf(m, __shfl_xor(m, d));
        if (tid == 0) shT = (m < 0.1f) ? 0.1f : (m + 1e-7f);
    }
    __syncthreads();
    const float T = shT;

    const long Rb = (long)b * RPB;
    for (int c = 0; c < CPB; ++c) {
        long i = Rb + (long)c * BS + tid;
        bool pred = (i < N) && ((track[i] ? 0.0f : score[i]) <= T);
        u64 bal = __ballot(pred);
        if (lane == 0) smask[c * 4 + w] = bal;   // linear word index b*WPC + c*4 + w
    }
    __syncthreads();
    if (tid < WPC) gmask[(long)b * WPC + tid] = smask[tid];
    if (tid == 0) {
        int c = 0;
        for (int k = 0; k < WPC; ++k) c += __popcll(smask[k]);
        cnts[b] = c;
    }
}

// ---------------- Node 3: forward-contiguous output writer ------------------
__global__ __launch_bounds__(BS)
void k_write(const float* __restrict__ x, const int* __restrict__ rsp,
             const u64* __restrict__ gmask, const int* __restrict__ cnts,
             int N, int B, int F, int G2, int OB,
             float* __restrict__ out_x, float* __restrict__ out_rs,
             float* __restrict__ out_old, float* __restrict__ out_idx,
             float* __restrict__ out_nsel) {
    const int b = blockIdx.x, tid = threadIdx.x;
    const int lane = tid & 63, wv = tid >> 6;
    const int Wall = G2 * WPC;

    __shared__ int srcRows[RPB];
    __shared__ int shCb0, shBase0, shTot;
    __shared__ long wsum[BS / 64];

    // ---------- appended boundary blocks: new_rs ----------
    if (b >= OB) {
        int sb = b - OB;
        int pos = rsp[sb];
        int cbP = pos / RPB;
        int within = pos - cbP * RPB;
        long sum = 0;
        for (int k = tid; k < cbP; k += BS) sum += cnts[k];
        if (tid == 0) {
            int fw = within >> 6, rem = within & 63;
            int wb = cbP * WPC;
            for (int k2 = 0; k2 < fw; ++k2) sum += __popcll(gmask[wb + k2]);
            if (rem) sum += __popcll(gmask[wb + fw] & ((1ull << rem) - 1ull));
        }
        for (int d = 32; d > 0; d >>= 1) sum += __shfl_down(sum, d);
        if (lane == 0) wsum[wv] = sum;
        __syncthreads();
        if (tid == 0) {
            long s = 0;
            for (int k = 0; k < BS / 64; ++k) s += wsum[k];
            out_rs[sb] = (float)s;
        }
        return;
    }

    const int D0 = b * RPB;
    const int D1 = min(N, D0 + RPB);

    // ---- phase 1 (wave 0): locate start count-block + exclusive base + total
    if (wv == 0) {
        int S = (G2 + 63) / 64;
        int lo = min(G2, lane * S), hi = min(G2, lane * S + S);
        int ssum = 0;
        for (int k = lo; k < hi; ++k) ssum += cnts[k];
        int incl = ssum;
        for (int d = 1; d < 64; d <<= 1) { int t = __shfl_up(incl, d); if (lane >= d) incl += t; }
        int sbase = incl - ssum;
        u64 m = __ballot(sbase <= D0);
        int H = 63 - __clzll(m);
        if (lane == H) {
            int run = sbase; int cb = lo;
            for (; cb < hi; ++cb) { int c = cnts[cb]; if (run + c > D0) break; run += c; }
            shCb0 = cb; shBase0 = run;
        }
        if (lane == 63) shTot = incl;
    }
    __syncthreads();
    const int total = shTot;
    const int selCnt = max(0, min(D1, total) - D0);

    if (b == 0 && tid == 0) { out_nsel[0] = (float)total; out_old[0] = (float)N; }

    // ---- phase 2 (wave 0): enumerate src rows for dst [D0, D0+selCnt) ----
    if (wv == 0 && selCnt > 0) {
        int wBase = shCb0 * WPC;
        long acc = shBase0;
        while (true) {
            int wi = wBase + lane;
            u64 word = (wi < Wall) ? gmask[wi] : 0ull;
            int p = __popcll(word);
            int incl = p;
            for (int d = 1; d < 64; d <<= 1) { int t = __shfl_up(incl, d); if (lane >= d) incl += t; }
            long wstart = acc + (incl - p);     // abs sel-pos of this word's first bit
            if (word && (wstart + p > (long)D0) && (wstart < (long)D0 + selCnt)) {
                u64 w2 = word; int j = 0;
                while (w2) {
                    int bit = __ffsll((long long)w2) - 1;
                    long slot = wstart + j - D0;
                    if (slot >= 0 && slot < selCnt) srcRows[slot] = wi * 64 + bit;
                    w2 &= w2 - 1; ++j;
                }
            }
            long wtot = __shfl(incl, 63);
            acc += wtot;
            wBase += 64;
            if (acc >= (long)D0 + selCnt || wBase >= Wall) break;
        }
    }
    __syncthreads();

    // ---- phase 3 (all threads): contiguous streaming writes ----
    const int nrows = D1 - D0;
    const int Fv = F >> 2;
    if ((F & 3) == 0 && Fv > 0 && (BS % Fv) == 0) {
        const f32x4* x4 = (const f32x4*)x;
        f32x4* o4 = (f32x4*)out_x + (long)D0 * Fv;
        const int rstep = BS / Fv;
        int r0 = tid / Fv, cc = tid - r0 * Fv;
        int r = r0;
        for (; r < selCnt; r += rstep)
            o4[(long)r * Fv + cc] = x4[(long)srcRows[r] * Fv + cc];
        f32x4 z = (f32x4)(0.0f);
        for (; r < nrows; r += rstep)
            o4[(long)r * Fv + cc] = z;
    } else {
        float* o = out_x + (long)D0 * F;
        int selE = selCnt * F, allE = nrows * F;
        int e = tid;
        for (; e < selE; e += BS) {
            int r = e / F, cc = e - r * F;
            o[e] = x[(long)srcRows[r] * F + cc];
        }
        for (; e < allE; e += BS) o[e] = 0.0f;
    }
    float* oi = out_idx + D0;
    int t2 = tid;
    for (; t2 < selCnt; t2 += BS) oi[t2] = (float)srcRows[t2];
    for (; t2 < nrows; t2 += BS) oi[t2] = -1.0f;
}

extern "C" void kernel_launch(void* const* d_in, const int* in_sizes, int n_in,
                              void* d_out, int out_size, void* d_ws, size_t ws_size,
                              hipStream_t stream) {
    const float* x     = (const float*)d_in[0];
    const float* score = (const float*)d_in[1];
    const int*   track = (const int*)d_in[2];
    const int*   rs    = (const int*)d_in[3];

    int N = in_sizes[1];            // rows
    int F = in_sizes[0] / N;        // 32
    int B = in_sizes[3] - 1;        // 64

    int G2 = (N + RPB - 1) / RPB;   // count-blocks == output write-blocks
    int OB = G2;

    int SPS = B > 0 ? (1024 / B) : 1;
    if (SPS < 1) SPS = 1;
    if (SPS > 64) SPS = 64;
    int G1 = B * SPS;

    // workspace layout
    float* part_min = (float*)d_ws;                 // G1 floats
    int*   cnts     = (int*)(part_min + G1);        // G2 ints
    u64*   gmask    = (u64*)(((uintptr_t)(cnts + G2) + 15) & ~(uintptr_t)15); // G2*WPC words

    // output layout (all float32 values)
    float* out      = (float*)d_out;
    long off_rs   = (long)N * F;
    long off_old  = off_rs + (B + 1);
    long off_idx  = off_old + 1;
    long off_nsel = off_idx + N;

    float* out_x    = out;
    float* out_rs   = out + off_rs;
    float* out_old  = out + off_old;
    float* out_idx  = out + off_idx;
    float* out_nsel = out + off_nsel;

    k_segmin<<<G1, BS, 0, stream>>>(score, track, rs, B, SPS, part_min);
    k_count<<<G2, BS, 0, stream>>>(score, track, part_min, N, B, SPS, gmask, cnts);
    k_write<<<OB + B + 1, BS, 0, stream>>>(x, rs, gmask, cnts, N, B, F, G2, OB,
                                           out_x, out_rs, out_old, out_idx, out_nsel);
}